// Round 5
// baseline (4455.672 us; speedup 1.0000x reference)
//
#include <hip/hip_runtime.h>
#include <hip/hip_bf16.h>

typedef __hip_bfloat16 bf16;
#define NT 256

__device__ __forceinline__ float b2f(bf16 v){ return __bfloat162float(v); }
__device__ __forceinline__ bf16 f2b(float v){ return __float2bfloat16(v); }
__device__ __forceinline__ float lrelu(float a){ return a>0.f ? a : 0.2f*a; }
__device__ __forceinline__ float sanf(float v){ return __builtin_isfinite(v) ? v : -12345.f; }

// dtype-flexible input load: f32in ? float : bf16
__device__ __forceinline__ float ld(const void* p, size_t i, int f32in){
  return f32in ? ((const float*)p)[i] : b2f(((const bf16*)p)[i]);
}

__device__ __forceinline__ float waveReduceSum(float v){
#pragma unroll
  for(int o=32;o>0;o>>=1) v += __shfl_down(v,o,64);
  return v;
}

// monotone float<->uint key for atomicMax on floats
__device__ __forceinline__ unsigned encf(float f){
  unsigned u=__float_as_uint(f);
  return (u&0x80000000u) ? ~u : (u|0x80000000u);
}
__device__ __forceinline__ float decf(unsigned e){
  unsigned u = (e&0x80000000u) ? (e&0x7fffffffu) : ~e;
  return __uint_as_float(u);
}
#define ENC_NEG_INF 0x00800000u

__device__ __forceinline__ unsigned clampi(int v, int n){
  unsigned u=(unsigned)v; return (u<(unsigned)n)?u:0u;
}

struct alignas(8) bf16x4 { bf16 a,b,c,d; };

// dual-precision h1 access (hm=1: f32, hm=0: bf16)
__device__ __forceinline__ void load_h1(const void* h1, int hm, unsigned node, float* dst){
  if(hm){
    const float4* p=(const float4*)((const float*)h1 + (size_t)node*16);
#pragma unroll
    for(int q=0;q<4;q++){ float4 v=p[q]; dst[q*4]=v.x; dst[q*4+1]=v.y; dst[q*4+2]=v.z; dst[q*4+3]=v.w; }
  }else{
    const bf16* p=(const bf16*)h1 + (size_t)node*16;
#pragma unroll
    for(int c=0;c<16;c++) dst[c]=b2f(p[c]);
  }
}

// ---------------- K0: zero stats, detect input dtype -> ((int*)stats)[7]
__global__ __launch_bounds__(64) void k_probe(const unsigned short* __restrict__ xraw,
                                              int nscan, float* __restrict__ stats){
  int t=threadIdx.x;
  int bad=0;
  for(int k=t*8;k<t*8+8;k++){
    if(k<nscan){
      unsigned short u=xraw[k];
      unsigned ex=(u>>7)&0xFF;
      bool plaus = (ex==0u) || (ex>=97u && ex<=157u);  // zero or |v| in ~[2^-30,2^30]
      if(!plaus) bad++;
    }
  }
#pragma unroll
  for(int o=32;o>0;o>>=1) bad += __shfl_down(bad,o,64);
  if(t==0){
    for(int i=0;i<7;i++) stats[i]=0.f;
    ((int*)stats)[7] = (bad>=8) ? 1 : 0;   // 1 => inputs are float32
  }
}

// ---------------- K1: sum of edge_attr (3 comps) -> stats[0..2]
__global__ __launch_bounds__(NT) void k_sum_ea(const void* __restrict__ ea,
                                               float* __restrict__ stats, int E){
  const int f32in = ((const int*)stats)[7];
  __shared__ float lds[16];
  float s0=0.f,s1=0.f,s2=0.f;
  for(size_t e = (size_t)blockIdx.x*NT + threadIdx.x; e < (size_t)E; e += (size_t)gridDim.x*NT){
    s0 += ld(ea,e*3+0,f32in); s1 += ld(ea,e*3+1,f32in); s2 += ld(ea,e*3+2,f32in);
  }
  int lane=threadIdx.x&63, wv=threadIdx.x>>6;
  s0=waveReduceSum(s0); s1=waveReduceSum(s1); s2=waveReduceSum(s2);
  if(lane==0){ lds[wv*4+0]=s0; lds[wv*4+1]=s1; lds[wv*4+2]=s2; }
  __syncthreads();
  if(threadIdx.x==0){
    float a0=0,a1=0,a2=0;
    for(int w=0;w<NT/64;w++){ a0+=lds[w*4]; a1+=lds[w*4+1]; a2+=lds[w*4+2]; }
    atomicAdd(&stats[0],a0); atomicAdd(&stats[1],a1); atomicAdd(&stats[2],a2);
  }
}

// ---------------- K2: h=x@W1, als, ald, amax seeded with enc(self alpha)
__global__ __launch_bounds__(NT) void k_node1(
    const void* __restrict__ x, const void* __restrict__ W1,
    const void* __restrict__ as1, const void* __restrict__ ad1,
    const void* __restrict__ We1, const void* __restrict__ ae1,
    const float* __restrict__ stats, float invE,
    float* __restrict__ h, float* __restrict__ als, float* __restrict__ ald,
    unsigned* __restrict__ amaxu, int N){
  const int f32in = ((const int*)stats)[7];
  __shared__ float sW1[64], sas[16], sad[16], sve[3];
  if(threadIdx.x<64) sW1[threadIdx.x]=ld(W1,threadIdx.x,f32in);
  if(threadIdx.x<16){ sas[threadIdx.x]=ld(as1,threadIdx.x,f32in); sad[threadIdx.x]=ld(ad1,threadIdx.x,f32in); }
  if(threadIdx.x<3){
    float v=0.f;
    for(int j=0;j<16;j++) v += ld(We1,threadIdx.x*16+j,f32in)*ld(ae1,j,f32in);
    sve[threadIdx.x]=v;
  }
  __syncthreads();
  int i = blockIdx.x*NT+threadIdx.x;
  if(i>=N) return;
  float xv[4];
#pragma unroll
  for(int k=0;k<4;k++) xv[k]=ld(x,(size_t)i*4+k,f32in);
  float hv[16], a_s=0.f, a_d=0.f;
#pragma unroll
  for(int j=0;j<16;j++){
    float v = xv[0]*sW1[j] + xv[1]*sW1[16+j] + xv[2]*sW1[32+j] + xv[3]*sW1[48+j];
    hv[j]=v; a_s += v*sas[j]; a_d += v*sad[j];
  }
  float aea = (stats[0]*sve[0] + stats[1]*sve[1] + stats[2]*sve[2])*invE;
  als[i]=a_s; ald[i]=a_d;
  amaxu[i]=encf(sanf(lrelu(a_s + a_d + aea)));
  float4* hp=(float4*)(h+(size_t)i*16);
#pragma unroll
  for(int q=0;q<4;q++){
    float4 v; v.x=hv[q*4]; v.y=hv[q*4+1]; v.z=hv[q*4+2]; v.w=hv[q*4+3];
    hp[q]=v;
  }
}

// ---------------- K3: layer-1 edge pass A: atomic enc-max of alpha into amax[d]
__global__ __launch_bounds__(NT) void k_edge1a(
    const int* __restrict__ idx, const void* __restrict__ ea,
    const void* __restrict__ We1, const void* __restrict__ ae1,
    const float* __restrict__ als, const float* __restrict__ ald,
    const float* __restrict__ stats,
    unsigned* __restrict__ amaxu, int E, int N){
  const int f32in = ((const int*)stats)[7];
  __shared__ float sve[3];
  if(threadIdx.x<3){
    float v=0.f;
    for(int j=0;j<16;j++) v += ld(We1,threadIdx.x*16+j,f32in)*ld(ae1,j,f32in);
    sve[threadIdx.x]=v;
  }
  __syncthreads();
  int e = blockIdx.x*NT+threadIdx.x;
  if(e>=E) return;
  unsigned s = clampi(idx[e],N), d = clampi(idx[E+e],N);
  float alpha = lrelu(als[s] + ald[d]
              + ld(ea,(size_t)e*3+0,f32in)*sve[0] + ld(ea,(size_t)e*3+1,f32in)*sve[1]
              + ld(ea,(size_t)e*3+2,f32in)*sve[2]);
  atomicMax(&amaxu[d], encf(sanf(alpha)));
}

// ---------------- K4: decode amax->float; init denom/acc with self-loop exp
__global__ __launch_bounds__(NT) void k_node1b(
    const float* __restrict__ als, const float* __restrict__ ald,
    const void* __restrict__ We1, const void* __restrict__ ae1,
    const float* __restrict__ stats, float invE,
    unsigned* amaxu, const float* __restrict__ h,
    float* __restrict__ denom, float* __restrict__ acc, int N){
  const int f32in = ((const int*)stats)[7];
  __shared__ float sve[3];
  if(threadIdx.x<3){
    float v=0.f;
    for(int j=0;j<16;j++) v += ld(We1,threadIdx.x*16+j,f32in)*ld(ae1,j,f32in);
    sve[threadIdx.x]=v;
  }
  __syncthreads();
  int i=blockIdx.x*NT+threadIdx.x;
  if(i>=N) return;
  float aea = (stats[0]*sve[0] + stats[1]*sve[1] + stats[2]*sve[2])*invE;
  float self = lrelu(als[i]+ald[i]+aea);
  float am = decf(amaxu[i]);
  ((float*)amaxu)[i] = am;
  float ex = expf(fminf(self - am, 0.f));
  denom[i]=ex;
  const float4* hp=(const float4*)(h+(size_t)i*16);
  float4* ap=(float4*)(acc+(size_t)i*16);
#pragma unroll
  for(int q=0;q<4;q++){
    float4 v=hp[q];
    float4 a; a.x=v.x*ex; a.y=v.y*ex; a.z=v.z*ex; a.w=v.w*ex;
    ap[q]=a;
  }
}

// ---------------- K5: layer-1 edge pass B: recompute alpha, exp scatter
__global__ __launch_bounds__(NT) void k_edge1b(
    const int* __restrict__ idx, const void* __restrict__ ea,
    const void* __restrict__ We1, const void* __restrict__ ae1,
    const float* __restrict__ als, const float* __restrict__ ald,
    const float* __restrict__ stats,
    const float* __restrict__ amaxf, const float* __restrict__ h,
    float* __restrict__ denom, float* __restrict__ acc, int E, int N){
  const int f32in = ((const int*)stats)[7];
  __shared__ float sve[3];
  if(threadIdx.x<3){
    float v=0.f;
    for(int j=0;j<16;j++) v += ld(We1,threadIdx.x*16+j,f32in)*ld(ae1,j,f32in);
    sve[threadIdx.x]=v;
  }
  __syncthreads();
  int e = blockIdx.x*NT+threadIdx.x;
  if(e>=E) return;
  unsigned s = clampi(idx[e],N), d = clampi(idx[E+e],N);
  float alpha = lrelu(als[s] + ald[d]
              + ld(ea,(size_t)e*3+0,f32in)*sve[0] + ld(ea,(size_t)e*3+1,f32in)*sve[1]
              + ld(ea,(size_t)e*3+2,f32in)*sve[2]);
  float ex = expf(fminf(alpha - amaxf[d], 0.f));
  atomicAdd(&denom[d], ex);
  const float4* hs = (const float4*)(h + (size_t)s*16);
  float* ac = acc + (size_t)d*16;
#pragma unroll
  for(int q=0;q<4;q++){
    float4 v=hs[q];
    atomicAdd(&ac[q*4+0], ex*v.x);
    atomicAdd(&ac[q*4+1], ex*v.y);
    atomicAdd(&ac[q*4+2], ex*v.z);
    atomicAdd(&ac[q*4+3], ex*v.w);
  }
}

// ---------------- K6: h1 = acc/denom + b1; h2 = h1@W2; layer-2 logits; amax seed
__global__ __launch_bounds__(NT) void k_node2(
    const float* __restrict__ acc, const float* __restrict__ denom,
    const void* __restrict__ b1, const void* __restrict__ W2,
    const void* __restrict__ as2, const void* __restrict__ ad2,
    const float* __restrict__ stats,
    void* __restrict__ h1, int hm, float* __restrict__ h2,
    float* __restrict__ als2, float* __restrict__ ald2,
    unsigned* __restrict__ amaxu, int N){
  const int f32in = ((const int*)stats)[7];
  __shared__ float sb1[16], sW2[32], sas2[2], sad2[2];
  if(threadIdx.x<16) sb1[threadIdx.x]=ld(b1,threadIdx.x,f32in);
  if(threadIdx.x<32) sW2[threadIdx.x]=ld(W2,threadIdx.x,f32in);
  if(threadIdx.x<2){ sas2[threadIdx.x]=ld(as2,threadIdx.x,f32in); sad2[threadIdx.x]=ld(ad2,threadIdx.x,f32in); }
  __syncthreads();
  int i=blockIdx.x*NT+threadIdx.x;
  if(i>=N) return;
  float inv = 1.f/(denom[i]+1e-16f);
  float h1v[16], t0=0.f, t1=0.f;
#pragma unroll
  for(int c=0;c<16;c++){
    float v = acc[(size_t)i*16+c]*inv + sb1[c];
    h1v[c]=v;
    t0 += v*sW2[c*2+0];
    t1 += v*sW2[c*2+1];
  }
  if(hm){
    float4* hp=(float4*)((float*)h1+(size_t)i*16);
#pragma unroll
    for(int q=0;q<4;q++){
      float4 v; v.x=h1v[q*4]; v.y=h1v[q*4+1]; v.z=h1v[q*4+2]; v.w=h1v[q*4+3];
      hp[q]=v;
    }
  }else{
    bf16* hp=(bf16*)h1+(size_t)i*16;
#pragma unroll
    for(int c=0;c<16;c++) hp[c]=f2b(h1v[c]);
  }
  h2[(size_t)i*2]=t0; h2[(size_t)i*2+1]=t1;
  als2[i]=t0*sas2[0]+t1*sas2[1];
  ald2[i]=t0*sad2[0]+t1*sad2[1];
  amaxu[i]=ENC_NEG_INF;
}

// shared preload + eval for the edge MLP
__device__ __forceinline__ void mlp_preload(float* sw,
    const void* mw0,const void* mb0,const void* mw1,const void* mb1,
    const void* mw2,const void* mb2,const void* mw3,const void* mb3,
    const void* We2,const void* ae2,int f32in){
  for(int t=threadIdx.x;t<560;t+=NT) sw[t]=ld(mw0,t,f32in);
  for(int t=threadIdx.x;t<256;t+=NT) sw[576+t]=ld(mw1,t,f32in);
  for(int t=threadIdx.x;t<128;t+=NT) sw[848+t]=ld(mw2,t,f32in);
  if(threadIdx.x<32) sw[984+threadIdx.x]=ld(mw3,threadIdx.x,f32in);
  if(threadIdx.x<16){ sw[560+threadIdx.x]=ld(mb0,threadIdx.x,f32in); sw[832+threadIdx.x]=ld(mb1,threadIdx.x,f32in); }
  if(threadIdx.x<8) sw[976+threadIdx.x]=ld(mb2,threadIdx.x,f32in);
  if(threadIdx.x<4){
    sw[1016+threadIdx.x]=ld(mb3,threadIdx.x,f32in);
    sw[1020+threadIdx.x]=ld(We2,threadIdx.x*2+0,f32in)*ld(ae2,0,f32in)
                        +ld(We2,threadIdx.x*2+1,f32in)*ld(ae2,1,f32in);
  }
  __syncthreads();
}

__device__ __forceinline__ void mlp_eval(const float* __restrict__ z, const float* __restrict__ sw, float* ev){
  const float* s_mw0=sw;      const float* s_mb0=sw+560;
  const float* s_mw1=sw+576;  const float* s_mb1=sw+832;
  const float* s_mw2=sw+848;  const float* s_mb2=sw+976;
  const float* s_mw3=sw+984;  const float* s_mb3=sw+1016;
  float t1v[16];
#pragma unroll
  for(int j=0;j<16;j++){
    float a=s_mb0[j];
#pragma unroll
    for(int i2=0;i2<35;i2++) a += z[i2]*s_mw0[i2*16+j];
    t1v[j]=fmaxf(a,0.f);
  }
  float t2v[16];
#pragma unroll
  for(int j=0;j<16;j++){
    float a=s_mb1[j];
#pragma unroll
    for(int i2=0;i2<16;i2++) a += t1v[i2]*s_mw1[i2*16+j];
    t2v[j]=fmaxf(a,0.f);
  }
  float t3v[8];
#pragma unroll
  for(int j=0;j<8;j++){
    float a=s_mb2[j];
#pragma unroll
    for(int i2=0;i2<16;i2++) a += t2v[i2]*s_mw2[i2*8+j];
    t3v[j]=fmaxf(a,0.f);
  }
#pragma unroll
  for(int j=0;j<4;j++){
    float a=s_mb3[j];
#pragma unroll
    for(int i2=0;i2<8;i2++) a += t3v[i2]*s_mw3[i2*4+j];
    ev[j]=a;
  }
}

// ---------------- K7: edge MLP + out1 log_softmax + alpha2 enc-max + mean(e)
__global__ __launch_bounds__(NT) void k_edge2(
    const int* __restrict__ idx, const void* __restrict__ ea,
    const void* __restrict__ h1, int hm,
    const float* __restrict__ als2, const float* __restrict__ ald2,
    const void* __restrict__ mw0,const void* __restrict__ mb0,
    const void* __restrict__ mw1,const void* __restrict__ mb1,
    const void* __restrict__ mw2,const void* __restrict__ mb2,
    const void* __restrict__ mw3,const void* __restrict__ mb3,
    const void* __restrict__ We2,const void* __restrict__ ae2,
    unsigned* __restrict__ amaxu,
    float* __restrict__ stats, void* __restrict__ d_out, int E, int N){
  const int f32in = ((const int*)stats)[7];
  __shared__ float sw[1040];
  __shared__ float s_red[16];
  mlp_preload(sw,mw0,mb0,mw1,mb1,mw2,mb2,mw3,mb3,We2,ae2,f32in);
  int e=blockIdx.x*NT+threadIdx.x;
  float e0=0.f,e1=0.f,e2=0.f,e3=0.f;
  if(e<E){
    unsigned s=clampi(idx[e],N), d=clampi(idx[E+e],N);
    float z[35];
    load_h1(h1,hm,s,z);
    z[16]=ld(ea,(size_t)e*3+0,f32in); z[17]=ld(ea,(size_t)e*3+1,f32in); z[18]=ld(ea,(size_t)e*3+2,f32in);
    load_h1(h1,hm,d,z+19);
    float ev[4];
    mlp_eval(z,sw,ev);
    e0=ev[0]; e1=ev[1]; e2=ev[2]; e3=ev[3];
    float m=fmaxf(fmaxf(ev[0],ev[1]),fmaxf(ev[2],ev[3]));
    float lse=m+logf(expf(ev[0]-m)+expf(ev[1]-m)+expf(ev[2]-m)+expf(ev[3]-m));
    if(f32in){
      float4 o; o.x=sanf(ev[0]-lse); o.y=sanf(ev[1]-lse); o.z=sanf(ev[2]-lse); o.w=sanf(ev[3]-lse);
      ((float4*)((float*)d_out + (size_t)2*N))[e]=o;
    }else{
      bf16x4 o; o.a=f2b(sanf(ev[0]-lse)); o.b=f2b(sanf(ev[1]-lse)); o.c=f2b(sanf(ev[2]-lse)); o.d=f2b(sanf(ev[3]-lse));
      ((bf16x4*)((bf16*)d_out + (size_t)2*N))[e]=o;
    }
    const float* s_ve2=sw+1020;
    float adot = ev[0]*s_ve2[0]+ev[1]*s_ve2[1]+ev[2]*s_ve2[2]+ev[3]*s_ve2[3];
    float a2 = sanf(lrelu(als2[s]+ald2[d]+adot));
    atomicMax(&amaxu[d], encf(a2));
  }
  int lane=threadIdx.x&63, wv=threadIdx.x>>6;
  e0=waveReduceSum(e0); e1=waveReduceSum(e1); e2=waveReduceSum(e2); e3=waveReduceSum(e3);
  __syncthreads();
  if(lane==0){ s_red[wv*4]=e0; s_red[wv*4+1]=e1; s_red[wv*4+2]=e2; s_red[wv*4+3]=e3; }
  __syncthreads();
  if(threadIdx.x==0){
    float a0=0,a1=0,a2=0,a3=0;
    for(int w=0;w<NT/64;w++){ a0+=s_red[w*4]; a1+=s_red[w*4+1]; a2+=s_red[w*4+2]; a3+=s_red[w*4+3]; }
    atomicAdd(&stats[3],a0); atomicAdd(&stats[4],a1); atomicAdd(&stats[5],a2); atomicAdd(&stats[6],a3);
  }
}

// ---------------- K8: fold self-loop alpha into amax, init denom2/acc2
__global__ __launch_bounds__(NT) void k_node2b(
    const float* __restrict__ stats, float invE,
    const float* __restrict__ als2, const float* __restrict__ ald2,
    const void* __restrict__ We2, const void* __restrict__ ae2,
    const float* __restrict__ h2,
    unsigned* amaxu, float* __restrict__ denom2, float* __restrict__ acc2, int N){
  const int f32in = ((const int*)stats)[7];
  __shared__ float s_ve2[4];
  if(threadIdx.x<4)
    s_ve2[threadIdx.x]=ld(We2,threadIdx.x*2+0,f32in)*ld(ae2,0,f32in)
                      +ld(We2,threadIdx.x*2+1,f32in)*ld(ae2,1,f32in);
  __syncthreads();
  int i=blockIdx.x*NT+threadIdx.x;
  if(i>=N) return;
  float adot = (stats[3]*s_ve2[0]+stats[4]*s_ve2[1]+stats[5]*s_ve2[2]+stats[6]*s_ve2[3])*invE;
  float self = lrelu(als2[i]+ald2[i]+adot);
  float am = fmaxf(decf(amaxu[i]), self);
  ((float*)amaxu)[i]=am;
  float ex = expf(fminf(self-am, 0.f));
  denom2[i]=ex;
  acc2[(size_t)i*2+0]=ex*h2[(size_t)i*2+0];
  acc2[(size_t)i*2+1]=ex*h2[(size_t)i*2+1];
}

// ---------------- K9: layer-2 edge pass B: recompute MLP + alpha2, exp scatter
__global__ __launch_bounds__(NT) void k_edge2b(
    const int* __restrict__ idx, const void* __restrict__ ea,
    const void* __restrict__ h1, int hm,
    const float* __restrict__ als2, const float* __restrict__ ald2,
    const void* __restrict__ mw0,const void* __restrict__ mb0,
    const void* __restrict__ mw1,const void* __restrict__ mb1,
    const void* __restrict__ mw2,const void* __restrict__ mb2,
    const void* __restrict__ mw3,const void* __restrict__ mb3,
    const void* __restrict__ We2,const void* __restrict__ ae2,
    const float* __restrict__ stats,
    const float* __restrict__ amaxf, const float* __restrict__ h2,
    float* __restrict__ denom2, float* __restrict__ acc2, int E, int N){
  const int f32in = ((const int*)stats)[7];
  __shared__ float sw[1040];
  mlp_preload(sw,mw0,mb0,mw1,mb1,mw2,mb2,mw3,mb3,We2,ae2,f32in);
  int e=blockIdx.x*NT+threadIdx.x;
  if(e>=E) return;
  unsigned s=clampi(idx[e],N), d=clampi(idx[E+e],N);
  float z[35];
  load_h1(h1,hm,s,z);
  z[16]=ld(ea,(size_t)e*3+0,f32in); z[17]=ld(ea,(size_t)e*3+1,f32in); z[18]=ld(ea,(size_t)e*3+2,f32in);
  load_h1(h1,hm,d,z+19);
  float ev[4];
  mlp_eval(z,sw,ev);
  const float* s_ve2=sw+1020;
  float adot = ev[0]*s_ve2[0]+ev[1]*s_ve2[1]+ev[2]*s_ve2[2]+ev[3]*s_ve2[3];
  float a2 = sanf(lrelu(als2[s]+ald2[d]+adot));
  float ex = expf(fminf(a2-amaxf[d], 0.f));
  atomicAdd(&denom2[d], ex);
  atomicAdd(&acc2[(size_t)d*2+0], ex*h2[(size_t)s*2+0]);
  atomicAdd(&acc2[(size_t)d*2+1], ex*h2[(size_t)s*2+1]);
}

// ---------------- K10: layer-2 epilogue + out0 log_softmax
__global__ __launch_bounds__(NT) void k_node3(
    const float* __restrict__ denom2, const float* __restrict__ acc2,
    const void* __restrict__ bias2, const float* __restrict__ stats,
    void* __restrict__ d_out, int N){
  const int f32in = ((const int*)stats)[7];
  __shared__ float s_b2[2];
  if(threadIdx.x<2) s_b2[threadIdx.x]=ld(bias2,threadIdx.x,f32in);
  __syncthreads();
  int i=blockIdx.x*NT+threadIdx.x;
  if(i>=N) return;
  float inv = 1.f/(denom2[i]+1e-16f);
  float o0=acc2[(size_t)i*2+0]*inv + s_b2[0];
  float o1=acc2[(size_t)i*2+1]*inv + s_b2[1];
  float m=fmaxf(o0,o1);
  float lse=m+logf(expf(o0-m)+expf(o1-m));
  float r0=sanf(o0-lse), r1=sanf(o1-lse);
  if(f32in){
    float* o=(float*)d_out;
    o[(size_t)i*2+0]=r0; o[(size_t)i*2+1]=r1;
  }else{
    bf16* o=(bf16*)d_out;
    o[(size_t)i*2+0]=f2b(r0); o[(size_t)i*2+1]=f2b(r1);
  }
}

extern "C" void kernel_launch(void* const* d_in, const int* in_sizes, int n_in,
                              void* d_out, int out_size, void* d_ws, size_t ws_size,
                              hipStream_t stream){
  const void* x   =d_in[0];
  const void* ea  =d_in[1];
  const void* W1  =d_in[2];
  const void* as1 =d_in[3];
  const void* ad1 =d_in[4];
  const void* We1 =d_in[5];
  const void* ae1 =d_in[6];
  const void* b1  =d_in[7];
  const void* mw0 =d_in[8];
  const void* mb0 =d_in[9];
  const void* mw1 =d_in[10];
  const void* mb1 =d_in[11];
  const void* mw2 =d_in[12];
  const void* mb2 =d_in[13];
  const void* mw3 =d_in[14];
  const void* mb3 =d_in[15];
  const void* W2  =d_in[16];
  const void* as2 =d_in[17];
  const void* ad2 =d_in[18];
  const void* We2 =d_in[19];
  const void* ae2 =d_in[20];
  const void* bias2=d_in[21];
  const int*  idx =(const int*)d_in[22];

  int N = in_sizes[0]/4;
  int E = in_sizes[1]/3;
  float invE = 1.f/(float)E;

  // ---- Persistent scratch in d_ws (floats):
  //   stats 8 | als N | ald N | amax N | den2 N | h2 2N | acc2 2N | h1 (16N f32 or 16N bf16)
  size_t needA = ((size_t)24*N + 8)*4;   // h1 in f32
  int hm = (ws_size >= needA) ? 1 : 0;   // 0 => h1 stored as bf16 (6.4 MB total)
  float*    F     = (float*)d_ws;
  float*    stats = F;
  float*    als   = F + 8;
  float*    ald   = als + N;
  unsigned* amaxu = (unsigned*)(ald + N);
  float*    amaxf = (float*)amaxu;
  float*    den2  = (float*)amaxu + N;
  float*    h2    = den2 + N;
  float*    acc2  = h2 + (size_t)2*N;
  void*     h1    = (void*)(acc2 + (size_t)2*N);

  // ---- Transient scratch (h 16N, acc 16N, den1 N floats) in the d_out tail,
  //      in the window [8N bytes, 4N+8E bytes) which is valid for both output
  //      dtypes and fully dead before k_edge2 writes the final out1 data.
  char*  wb  = (char*)d_out + (size_t)8*N;
  float* h   = (float*)wb;
  float* acc = h + (size_t)16*N;
  float* den1= acc + (size_t)16*N;
  // window capacity check: 33N floats vs (8E-4N) bytes; fall back to ws tail if needed
  if((size_t)33*N*4 > (size_t)8*E - (size_t)4*N){
    float* t = (float*)h1 + (hm ? (size_t)16*N : (size_t)8*N);
    h=t; acc=h+(size_t)16*N; den1=acc+(size_t)16*N;
  }

  int nbN = (N+NT-1)/NT, nbE=(E+NT-1)/NT;
  int nscan = in_sizes[0]*2; if(nscan>512) nscan=512;  // raw 16-bit words of x
  k_probe  <<<1,64,0,stream>>>((const unsigned short*)x, nscan, stats);
  k_sum_ea <<<512,NT,0,stream>>>(ea, stats, E);
  k_node1  <<<nbN,NT,0,stream>>>(x,W1,as1,ad1,We1,ae1,stats,invE,h,als,ald,amaxu,N);
  k_edge1a <<<nbE,NT,0,stream>>>(idx,ea,We1,ae1,als,ald,stats,amaxu,E,N);
  k_node1b <<<nbN,NT,0,stream>>>(als,ald,We1,ae1,stats,invE,amaxu,h,den1,acc,N);
  k_edge1b <<<nbE,NT,0,stream>>>(idx,ea,We1,ae1,als,ald,stats,amaxf,h,den1,acc,E,N);
  k_node2  <<<nbN,NT,0,stream>>>(acc,den1,b1,W2,as2,ad2,stats,h1,hm,h2,als,ald,amaxu,N);
  k_edge2  <<<nbE,NT,0,stream>>>(idx,ea,h1,hm,als,ald,mw0,mb0,mw1,mb1,mw2,mb2,mw3,mb3,
                                 We2,ae2,amaxu,stats,d_out,E,N);
  k_node2b <<<nbN,NT,0,stream>>>(stats,invE,als,ald,We2,ae2,h2,amaxu,den2,acc2,N);
  k_edge2b <<<nbE,NT,0,stream>>>(idx,ea,h1,hm,als,ald,mw0,mb0,mw1,mb1,mw2,mb2,mw3,mb3,
                                 We2,ae2,stats,amaxf,h2,den2,acc2,E,N);
  k_node3  <<<nbN,NT,0,stream>>>(den2,acc2,bias2,stats,d_out,N);
}

// Round 6
// 1825.383 us; speedup vs baseline: 2.4410x; 2.4410x over previous
//
#include <hip/hip_runtime.h>
#include <hip/hip_bf16.h>

typedef __hip_bfloat16 bf16;
typedef unsigned long long ull;
#define NT 256

__device__ __forceinline__ float b2f(bf16 v){ return __bfloat162float(v); }
__device__ __forceinline__ bf16 f2b(float v){ return __float2bfloat16(v); }
__device__ __forceinline__ float lrelu(float a){ return a>0.f ? a : 0.2f*a; }
__device__ __forceinline__ float sanf(float v){ return __builtin_isfinite(v) ? v : -12345.f; }
__device__ __forceinline__ float us2f(unsigned short u){ return __uint_as_float(((unsigned)u)<<16); }

// dtype-flexible input load: f32in ? float : bf16
__device__ __forceinline__ float ld(const void* p, size_t i, int f32in){
  return f32in ? ((const float*)p)[i] : b2f(((const bf16*)p)[i]);
}

__device__ __forceinline__ float waveReduceSum(float v){
#pragma unroll
  for(int o=32;o>0;o>>=1) v += __shfl_down(v,o,64);
  return v;
}

// monotone float<->uint key for atomicMax on floats
__device__ __forceinline__ unsigned encf(float f){
  unsigned u=__float_as_uint(f);
  return (u&0x80000000u) ? ~u : (u|0x80000000u);
}
__device__ __forceinline__ float decf(unsigned e){
  unsigned u = (e&0x80000000u) ? (e&0x7fffffffu) : ~e;
  return __uint_as_float(u);
}
#define ENC_NEG_INF 0x00800000u

__device__ __forceinline__ unsigned clampi(int v, int n){
  unsigned u=(unsigned)v; return (u<(unsigned)n)?u:0u;
}

// vectorized bf16 h1 row load (16 ch = 4x 8B)
__device__ __forceinline__ void load_h1v(const bf16* h1, unsigned node, float* dst){
  const ull* p=(const ull*)(h1+(size_t)node*16);
#pragma unroll
  for(int q=0;q<4;q++){
    ull v=p[q];
    dst[q*4+0]=us2f((unsigned short)v);        dst[q*4+1]=us2f((unsigned short)(v>>16));
    dst[q*4+2]=us2f((unsigned short)(v>>32));  dst[q*4+3]=us2f((unsigned short)(v>>48));
  }
}
// x row (4 ch) load, dtype-flex
__device__ __forceinline__ void load_x4(const void* x, unsigned n, int f32in, float* o){
  if(f32in){ float4 v=((const float4*)x)[n]; o[0]=v.x;o[1]=v.y;o[2]=v.z;o[3]=v.w; }
  else{
    ull v=((const ull*)x)[n];
    o[0]=us2f((unsigned short)v);       o[1]=us2f((unsigned short)(v>>16));
    o[2]=us2f((unsigned short)(v>>32)); o[3]=us2f((unsigned short)(v>>48));
  }
}

// ---------------- K0: zero stats, detect input dtype -> ((int*)stats)[7]
__global__ __launch_bounds__(64) void k_probe(const unsigned short* __restrict__ xraw,
                                              int nscan, float* __restrict__ stats){
  int t=threadIdx.x;
  int bad=0;
  for(int k=t*8;k<t*8+8;k++){
    if(k<nscan){
      unsigned short u=xraw[k];
      unsigned ex=(u>>7)&0xFF;
      bool plaus = (ex==0u) || (ex>=97u && ex<=157u);
      if(!plaus) bad++;
    }
  }
#pragma unroll
  for(int o=32;o>0;o>>=1) bad += __shfl_down(bad,o,64);
  if(t==0){
    for(int i=0;i<7;i++) stats[i]=0.f;
    ((int*)stats)[7] = (bad>=8) ? 1 : 0;
  }
}

// ---------------- K1: histogram of destinations + edge_attr sums -> stats[0..2]
__global__ __launch_bounds__(NT) void k_prep(const void* __restrict__ ea,
                                             const int* __restrict__ idx,
                                             int* __restrict__ rowc,
                                             float* __restrict__ stats, int E, int N){
  const int f32in=((const int*)stats)[7];
  __shared__ float lds[16];
  float s0=0.f,s1=0.f,s2=0.f;
  for(size_t e=(size_t)blockIdx.x*NT+threadIdx.x; e<(size_t)E; e+=(size_t)gridDim.x*NT){
    s0+=ld(ea,e*3+0,f32in); s1+=ld(ea,e*3+1,f32in); s2+=ld(ea,e*3+2,f32in);
    unsigned d=clampi(idx[(size_t)E+e],N);
    atomicAdd(&rowc[d],1);
  }
  int lane=threadIdx.x&63, wv=threadIdx.x>>6;
  s0=waveReduceSum(s0); s1=waveReduceSum(s1); s2=waveReduceSum(s2);
  if(lane==0){ lds[wv*4+0]=s0; lds[wv*4+1]=s1; lds[wv*4+2]=s2; }
  __syncthreads();
  if(threadIdx.x==0){
    float a0=0,a1=0,a2=0;
    for(int w=0;w<NT/64;w++){ a0+=lds[w*4]; a1+=lds[w*4+1]; a2+=lds[w*4+2]; }
    atomicAdd(&stats[0],a0); atomicAdd(&stats[1],a1); atomicAdd(&stats[2],a2);
  }
}

// ---------------- K2: als/ald per node
__global__ __launch_bounds__(NT) void k_node1(
    const void* __restrict__ x, const void* __restrict__ W1,
    const void* __restrict__ as1, const void* __restrict__ ad1,
    const float* __restrict__ stats,
    float* __restrict__ als, float* __restrict__ ald, int N){
  const int f32in=((const int*)stats)[7];
  __shared__ float sW1[64], sas[16], sad[16];
  if(threadIdx.x<64) sW1[threadIdx.x]=ld(W1,threadIdx.x,f32in);
  if(threadIdx.x<16){ sas[threadIdx.x]=ld(as1,threadIdx.x,f32in); sad[threadIdx.x]=ld(ad1,threadIdx.x,f32in); }
  __syncthreads();
  int i=blockIdx.x*NT+threadIdx.x;
  if(i>=N) return;
  float xv[4]; load_x4(x,(unsigned)i,f32in,xv);
  float a_s=0.f,a_d=0.f;
#pragma unroll
  for(int j=0;j<16;j++){
    float v=xv[0]*sW1[j]+xv[1]*sW1[16+j]+xv[2]*sW1[32+j]+xv[3]*sW1[48+j];
    a_s+=v*sas[j]; a_d+=v*sad[j];
  }
  als[i]=a_s; ald[i]=a_d;
}

// ---------------- scan (3 kernels): rowc hist -> exclusive starts
__global__ __launch_bounds__(NT) void k_scan1(const int* __restrict__ rowc, int* __restrict__ bsum, int N){
  __shared__ int sm[NT];
  int i=blockIdx.x*NT+threadIdx.x;
  sm[threadIdx.x]=(i<N)?rowc[i]:0;
  __syncthreads();
  for(int o=NT/2;o>0;o>>=1){ if(threadIdx.x<o) sm[threadIdx.x]+=sm[threadIdx.x+o]; __syncthreads(); }
  if(threadIdx.x==0) bsum[blockIdx.x]=sm[0];
}
__global__ __launch_bounds__(1024) void k_scan2(int* __restrict__ bsum, int NB){
  __shared__ int sm[1024];
  int i=threadIdx.x;
  int v=(i<NB)?bsum[i]:0;
  sm[i]=v; __syncthreads();
  for(int o=1;o<1024;o<<=1){
    int t=(i>=o)?sm[i-o]:0; __syncthreads();
    sm[i]+=t; __syncthreads();
  }
  if(i<NB) bsum[i]=(i==0)?0:sm[i-1];
}
__global__ __launch_bounds__(NT) void k_scan3(int* __restrict__ rowc, const int* __restrict__ bsum, int N){
  __shared__ int sm[NT];
  int i=blockIdx.x*NT+threadIdx.x;
  int v=(i<N)?rowc[i]:0;
  sm[threadIdx.x]=v; __syncthreads();
  for(int o=1;o<NT;o<<=1){
    int t=(threadIdx.x>=o)?sm[threadIdx.x-o]:0; __syncthreads();
    sm[threadIdx.x]+=t; __syncthreads();
  }
  if(i<N) rowc[i]=bsum[blockIdx.x]+sm[threadIdx.x]-v;   // exclusive start
}

// ---------------- K3: scatter packed {src, alpha_partial} into CSR slots; rowc -> end
__global__ __launch_bounds__(NT) void k_scatter(
    const int* __restrict__ idx, const void* __restrict__ ea,
    const void* __restrict__ We1, const void* __restrict__ ae1,
    const float* __restrict__ als, const float* __restrict__ stats,
    int* __restrict__ rowc, ull* __restrict__ csr, int E, int N){
  const int f32in=((const int*)stats)[7];
  __shared__ float sve[3];
  if(threadIdx.x<3){
    float v=0.f;
    for(int j=0;j<16;j++) v+=ld(We1,threadIdx.x*16+j,f32in)*ld(ae1,j,f32in);
    sve[threadIdx.x]=v;
  }
  __syncthreads();
  int e=blockIdx.x*NT+threadIdx.x;
  if(e>=E) return;
  unsigned s=clampi(idx[e],N), d=clampi(idx[(size_t)E+e],N);
  float ap = als[s] + ld(ea,(size_t)e*3+0,f32in)*sve[0]
                    + ld(ea,(size_t)e*3+1,f32in)*sve[1]
                    + ld(ea,(size_t)e*3+2,f32in)*sve[2];
  int pos=atomicAdd(&rowc[d],1);
  csr[pos] = (ull)s | ((ull)__float_as_uint(ap)<<32);
}

// ---------------- K4: gather-aggregate layer-1 softmax; write h1(bf16), h2, als2, ald2
// 16 lanes per node; 4 nodes per wave; 16 nodes per block.
__global__ __launch_bounds__(NT) void k_gather1(
    const ull* __restrict__ csr, const int* __restrict__ rowe,
    const float* __restrict__ als, const float* __restrict__ ald,
    const void* __restrict__ x, const void* __restrict__ W1, const void* __restrict__ b1,
    const void* __restrict__ W2, const void* __restrict__ as2, const void* __restrict__ ad2,
    const void* __restrict__ We1, const void* __restrict__ ae1,
    const float* __restrict__ stats, float invE,
    bf16* __restrict__ h1, float* __restrict__ h2,
    float* __restrict__ als2, float* __restrict__ ald2, int N){
  const int f32in=((const int*)stats)[7];
  __shared__ float sW1[64], sb1[16], sW2[32], sas2[2], sad2[2], saea[1];
  if(threadIdx.x<64) sW1[threadIdx.x]=ld(W1,threadIdx.x,f32in);
  if(threadIdx.x<16) sb1[threadIdx.x]=ld(b1,threadIdx.x,f32in);
  if(threadIdx.x<32) sW2[threadIdx.x]=ld(W2,threadIdx.x,f32in);
  if(threadIdx.x<2){ sas2[threadIdx.x]=ld(as2,threadIdx.x,f32in); sad2[threadIdx.x]=ld(ad2,threadIdx.x,f32in); }
  if(threadIdx.x==0){
    float a=0.f;
    for(int k=0;k<3;k++){
      float v=0.f;
      for(int j=0;j<16;j++) v+=ld(We1,k*16+j,f32in)*ld(ae1,j,f32in);
      a+=stats[k]*v;
    }
    saea[0]=a*invE;
  }
  __syncthreads();
  int n=blockIdx.x*16+(threadIdx.x>>4);
  int c=threadIdx.x&15;
  if(n>=N) return;
  int end=rowe[n];
  int start=(n==0)?0:rowe[n-1];
  float aldn=ald[n], alsn=als[n];
  float aself=lrelu(alsn+aldn+saea[0]);
  // phase A: segment max (strided over slots)
  float m=aself;
  for(int k=start+c;k<end;k+=16){
    float ap=__uint_as_float((unsigned)(csr[k]>>32));
    m=fmaxf(m,lrelu(ap+aldn));
  }
#pragma unroll
  for(int o=1;o<16;o<<=1) m=fmaxf(m,__shfl_xor(m,o,64));
  // self contribution
  float xv[4]; load_x4(x,(unsigned)n,f32in,xv);
  float hc_self=xv[0]*sW1[c]+xv[1]*sW1[16+c]+xv[2]*sW1[32+c]+xv[3]*sW1[48+c];
  float exs=expf(fminf(aself-m,0.f));
  float den=exs, acc=exs*hc_self;
  // phase B: serial over slots, lane c = channel
  for(int k=start;k<end;k++){
    ull v=csr[k];
    unsigned src=(unsigned)(v&0xffffffffu);
    float ap=__uint_as_float((unsigned)(v>>32));
    float ex=expf(fminf(lrelu(ap+aldn)-m,0.f));
    den+=ex;
    float xs[4]; load_x4(x,src,f32in,xs);
    float hc=xs[0]*sW1[c]+xs[1]*sW1[16+c]+xs[2]*sW1[32+c]+xs[3]*sW1[48+c];
    acc+=ex*hc;
  }
  float inv=1.f/(den+1e-16f);
  float h1c=acc*inv+sb1[c];
  h1[(size_t)n*16+c]=f2b(h1c);
  float r0=h1c*sW2[c*2+0], r1=h1c*sW2[c*2+1];
#pragma unroll
  for(int o=1;o<16;o<<=1){ r0+=__shfl_xor(r0,o,64); r1+=__shfl_xor(r1,o,64); }
  if(c==0){
    h2[(size_t)n*2+0]=r0; h2[(size_t)n*2+1]=r1;
    als2[n]=r0*sas2[0]+r1*sas2[1];
    ald2[n]=r0*sad2[0]+r1*sad2[1];
  }
}

// ---------------- K5: seed layer-2 amax (row region is now dead)
__global__ __launch_bounds__(NT) void k_seed(unsigned* __restrict__ amaxu, int N){
  int i=blockIdx.x*NT+threadIdx.x;
  if(i<N) amaxu[i]=ENC_NEG_INF;
}

// ---------------- edge-MLP shared preload / eval
__device__ __forceinline__ void mlp_preload(float* sw,
    const void* mw0,const void* mb0,const void* mw1,const void* mb1,
    const void* mw2,const void* mb2,const void* mw3,const void* mb3,
    const void* We2,const void* ae2,int f32in){
  for(int t=threadIdx.x;t<560;t+=NT) sw[t]=ld(mw0,t,f32in);
  for(int t=threadIdx.x;t<256;t+=NT) sw[576+t]=ld(mw1,t,f32in);
  for(int t=threadIdx.x;t<128;t+=NT) sw[848+t]=ld(mw2,t,f32in);
  if(threadIdx.x<32) sw[984+threadIdx.x]=ld(mw3,threadIdx.x,f32in);
  if(threadIdx.x<16){ sw[560+threadIdx.x]=ld(mb0,threadIdx.x,f32in); sw[832+threadIdx.x]=ld(mb1,threadIdx.x,f32in); }
  if(threadIdx.x<8) sw[976+threadIdx.x]=ld(mb2,threadIdx.x,f32in);
  if(threadIdx.x<4){
    sw[1016+threadIdx.x]=ld(mb3,threadIdx.x,f32in);
    sw[1020+threadIdx.x]=ld(We2,threadIdx.x*2+0,f32in)*ld(ae2,0,f32in)
                        +ld(We2,threadIdx.x*2+1,f32in)*ld(ae2,1,f32in);
  }
  __syncthreads();
}

__device__ __forceinline__ void mlp_eval(const float* __restrict__ z, const float* __restrict__ sw, float* ev){
  const float* s_mw0=sw;      const float* s_mb0=sw+560;
  const float* s_mw1=sw+576;  const float* s_mb1=sw+832;
  const float* s_mw2=sw+848;  const float* s_mb2=sw+976;
  const float* s_mw3=sw+984;  const float* s_mb3=sw+1016;
  float t1v[16];
#pragma unroll
  for(int j=0;j<16;j++){
    float a=s_mb0[j];
#pragma unroll
    for(int i2=0;i2<35;i2++) a+=z[i2]*s_mw0[i2*16+j];
    t1v[j]=fmaxf(a,0.f);
  }
  float t2v[16];
#pragma unroll
  for(int j=0;j<16;j++){
    float a=s_mb1[j];
#pragma unroll
    for(int i2=0;i2<16;i2++) a+=t1v[i2]*s_mw1[i2*16+j];
    t2v[j]=fmaxf(a,0.f);
  }
  float t3v[8];
#pragma unroll
  for(int j=0;j<8;j++){
    float a=s_mb2[j];
#pragma unroll
    for(int i2=0;i2<16;i2++) a+=t2v[i2]*s_mw2[i2*8+j];
    t3v[j]=fmaxf(a,0.f);
  }
#pragma unroll
  for(int j=0;j<4;j++){
    float a=s_mb3[j];
#pragma unroll
    for(int i2=0;i2<8;i2++) a+=t3v[i2]*s_mw3[i2*4+j];
    ev[j]=a;
  }
}

// ---------------- K6: edge MLP + out1 log_softmax + alpha2 enc-max + mean(e)
__global__ __launch_bounds__(NT) void k_edge2(
    const int* __restrict__ idx, const void* __restrict__ ea,
    const bf16* __restrict__ h1,
    const float* __restrict__ als2, const float* __restrict__ ald2,
    const void* mw0,const void* mb0,const void* mw1,const void* mb1,
    const void* mw2,const void* mb2,const void* mw3,const void* mb3,
    const void* We2,const void* ae2,
    unsigned* __restrict__ amaxu,
    float* __restrict__ stats, void* __restrict__ d_out, int E, int N){
  const int f32in=((const int*)stats)[7];
  __shared__ float sw[1040];
  __shared__ float s_red[16];
  mlp_preload(sw,mw0,mb0,mw1,mb1,mw2,mb2,mw3,mb3,We2,ae2,f32in);
  int e=blockIdx.x*NT+threadIdx.x;
  float e0=0.f,e1=0.f,e2=0.f,e3=0.f;
  if(e<E){
    unsigned s=clampi(idx[e],N), d=clampi(idx[(size_t)E+e],N);
    float z[35];
    load_h1v(h1,s,z);
    z[16]=ld(ea,(size_t)e*3+0,f32in); z[17]=ld(ea,(size_t)e*3+1,f32in); z[18]=ld(ea,(size_t)e*3+2,f32in);
    load_h1v(h1,d,z+19);
    float ev[4];
    mlp_eval(z,sw,ev);
    e0=ev[0]; e1=ev[1]; e2=ev[2]; e3=ev[3];
    float m=fmaxf(fmaxf(ev[0],ev[1]),fmaxf(ev[2],ev[3]));
    float lse=m+logf(expf(ev[0]-m)+expf(ev[1]-m)+expf(ev[2]-m)+expf(ev[3]-m));
    if(f32in){
      float4 o; o.x=sanf(ev[0]-lse); o.y=sanf(ev[1]-lse); o.z=sanf(ev[2]-lse); o.w=sanf(ev[3]-lse);
      ((float4*)((float*)d_out+(size_t)2*N))[e]=o;
    }else{
      ull o = ((ull)(unsigned short)(__float_as_uint(sanf(ev[0]-lse))>>16))
            | ((ull)(unsigned short)(__float_as_uint(sanf(ev[1]-lse))>>16)<<16)
            | ((ull)(unsigned short)(__float_as_uint(sanf(ev[2]-lse))>>16)<<32)
            | ((ull)(unsigned short)(__float_as_uint(sanf(ev[3]-lse))>>16)<<48);
      // use round-to-nearest instead of truncation: rebuild via f2b
      bf16 b0=f2b(sanf(ev[0]-lse)), b1=f2b(sanf(ev[1]-lse)), b2=f2b(sanf(ev[2]-lse)), b3=f2b(sanf(ev[3]-lse));
      bf16* p=(bf16*)d_out+(size_t)2*N+(size_t)e*4;
      p[0]=b0; p[1]=b1; p[2]=b2; p[3]=b3;
      (void)o;
    }
    const float* s_ve2=sw+1020;
    float adot=ev[0]*s_ve2[0]+ev[1]*s_ve2[1]+ev[2]*s_ve2[2]+ev[3]*s_ve2[3];
    float a2=sanf(lrelu(als2[s]+ald2[d]+adot));
    atomicMax(&amaxu[d],encf(a2));
  }
  int lane=threadIdx.x&63, wv=threadIdx.x>>6;
  e0=waveReduceSum(e0); e1=waveReduceSum(e1); e2=waveReduceSum(e2); e3=waveReduceSum(e3);
  __syncthreads();
  if(lane==0){ s_red[wv*4]=e0; s_red[wv*4+1]=e1; s_red[wv*4+2]=e2; s_red[wv*4+3]=e3; }
  __syncthreads();
  if(threadIdx.x==0){
    float a0=0,a1=0,a2=0,a3=0;
    for(int w=0;w<NT/64;w++){ a0+=s_red[w*4]; a1+=s_red[w*4+1]; a2+=s_red[w*4+2]; a3+=s_red[w*4+3]; }
    atomicAdd(&stats[3],a0); atomicAdd(&stats[4],a1); atomicAdd(&stats[5],a2); atomicAdd(&stats[6],a3);
  }
}

// ---------------- K7: fold self-loop alpha into amax, init den2/acc2
__global__ __launch_bounds__(NT) void k_node2b(
    const float* __restrict__ stats, float invE,
    const float* __restrict__ als2, const float* __restrict__ ald2,
    const void* __restrict__ We2, const void* __restrict__ ae2,
    const float* __restrict__ h2,
    unsigned* amaxu, float* __restrict__ denom2, float* __restrict__ acc2, int N){
  const int f32in=((const int*)stats)[7];
  __shared__ float s_ve2[4];
  if(threadIdx.x<4)
    s_ve2[threadIdx.x]=ld(We2,threadIdx.x*2+0,f32in)*ld(ae2,0,f32in)
                      +ld(We2,threadIdx.x*2+1,f32in)*ld(ae2,1,f32in);
  __syncthreads();
  int i=blockIdx.x*NT+threadIdx.x;
  if(i>=N) return;
  float adot=(stats[3]*s_ve2[0]+stats[4]*s_ve2[1]+stats[5]*s_ve2[2]+stats[6]*s_ve2[3])*invE;
  float self=lrelu(als2[i]+ald2[i]+adot);
  float am=fmaxf(decf(amaxu[i]),self);
  ((float*)amaxu)[i]=am;
  float ex=expf(fminf(self-am,0.f));
  denom2[i]=ex;
  acc2[(size_t)i*2+0]=ex*h2[(size_t)i*2+0];
  acc2[(size_t)i*2+1]=ex*h2[(size_t)i*2+1];
}

// ---------------- K8: layer-2 edge pass B: recompute MLP + alpha2, exp scatter
__global__ __launch_bounds__(NT) void k_edge2b(
    const int* __restrict__ idx, const void* __restrict__ ea,
    const bf16* __restrict__ h1,
    const float* __restrict__ als2, const float* __restrict__ ald2,
    const void* mw0,const void* mb0,const void* mw1,const void* mb1,
    const void* mw2,const void* mb2,const void* mw3,const void* mb3,
    const void* We2,const void* ae2,
    const float* __restrict__ stats,
    const float* __restrict__ amaxf, const float* __restrict__ h2,
    float* __restrict__ denom2, float* __restrict__ acc2, int E, int N){
  const int f32in=((const int*)stats)[7];
  __shared__ float sw[1040];
  mlp_preload(sw,mw0,mb0,mw1,mb1,mw2,mb2,mw3,mb3,We2,ae2,f32in);
  int e=blockIdx.x*NT+threadIdx.x;
  if(e>=E) return;
  unsigned s=clampi(idx[e],N), d=clampi(idx[(size_t)E+e],N);
  float z[35];
  load_h1v(h1,s,z);
  z[16]=ld(ea,(size_t)e*3+0,f32in); z[17]=ld(ea,(size_t)e*3+1,f32in); z[18]=ld(ea,(size_t)e*3+2,f32in);
  load_h1v(h1,d,z+19);
  float ev[4];
  mlp_eval(z,sw,ev);
  const float* s_ve2=sw+1020;
  float adot=ev[0]*s_ve2[0]+ev[1]*s_ve2[1]+ev[2]*s_ve2[2]+ev[3]*s_ve2[3];
  float a2=sanf(lrelu(als2[s]+ald2[d]+adot));
  float ex=expf(fminf(a2-amaxf[d],0.f));
  atomicAdd(&denom2[d],ex);
  atomicAdd(&acc2[(size_t)d*2+0],ex*h2[(size_t)s*2+0]);
  atomicAdd(&acc2[(size_t)d*2+1],ex*h2[(size_t)s*2+1]);
}

// ---------------- K9: layer-2 epilogue + out0 log_softmax
__global__ __launch_bounds__(NT) void k_node3(
    const float* __restrict__ denom2, const float* __restrict__ acc2,
    const void* __restrict__ bias2, const float* __restrict__ stats,
    void* __restrict__ d_out, int N){
  const int f32in=((const int*)stats)[7];
  __shared__ float s_b2[2];
  if(threadIdx.x<2) s_b2[threadIdx.x]=ld(bias2,threadIdx.x,f32in);
  __syncthreads();
  int i=blockIdx.x*NT+threadIdx.x;
  if(i>=N) return;
  float inv=1.f/(denom2[i]+1e-16f);
  float o0=acc2[(size_t)i*2+0]*inv+s_b2[0];
  float o1=acc2[(size_t)i*2+1]*inv+s_b2[1];
  float m=fmaxf(o0,o1);
  float lse=m+logf(expf(o0-m)+expf(o1-m));
  float r0=sanf(o0-lse), r1=sanf(o1-lse);
  if(f32in){
    float* o=(float*)d_out;
    o[(size_t)i*2+0]=r0; o[(size_t)i*2+1]=r1;
  }else{
    bf16* o=(bf16*)d_out;
    o[(size_t)i*2+0]=f2b(r0); o[(size_t)i*2+1]=f2b(r1);
  }
}

extern "C" void kernel_launch(void* const* d_in, const int* in_sizes, int n_in,
                              void* d_out, int out_size, void* d_ws, size_t ws_size,
                              hipStream_t stream){
  const void* x   =d_in[0];
  const void* ea  =d_in[1];
  const void* W1  =d_in[2];
  const void* as1 =d_in[3];
  const void* ad1 =d_in[4];
  const void* We1 =d_in[5];
  const void* ae1 =d_in[6];
  const void* b1  =d_in[7];
  const void* mw0 =d_in[8];
  const void* mb0 =d_in[9];
  const void* mw1 =d_in[10];
  const void* mb1 =d_in[11];
  const void* mw2 =d_in[12];
  const void* mb2 =d_in[13];
  const void* mw3 =d_in[14];
  const void* mb3 =d_in[15];
  const void* W2  =d_in[16];
  const void* as2 =d_in[17];
  const void* ad2 =d_in[18];
  const void* We2 =d_in[19];
  const void* ae2 =d_in[20];
  const void* bias2=d_in[21];
  const int*  idx =(const int*)d_in[22];

  int N=in_sizes[0]/4;
  int E=in_sizes[1]/3;
  float invE=1.f/(float)E;

  // ---- ws layout (floats), total (16N+8)*4 bytes = 6.40 MB @ N=100k (== R5-proven usage)
  float*    F     =(float*)d_ws;
  float*    stats =F;                         // 8
  float*    als   =F+8;                       // N   (als2 aliases after gather1)
  float*    ald   =als+N;                     // N   (den2 aliases after gather1)
  float*    ald2  =ald+N;                     // N
  int*      rowc  =(int*)(ald2+N);            // N   (hist -> start -> end -> amax2)
  unsigned* amaxu =(unsigned*)rowc;
  float*    amaxf =(float*)rowc;
  bf16*     h1    =(bf16*)(rowc+N);           // 16N bf16 = 8N floats
  float*    h2    =(float*)(h1+(size_t)16*N); // 2N
  float*    acc2  =h2+(size_t)2*N;            // 2N
  float*    den2  =ald;

  // ---- CSR (packed {src, alpha_partial}, 8B x E) in d_out at byte offset 4N:
  //      dead before k_edge2 writes out1 and before k_node3 writes out0.
  ull* csr =(ull*)((char*)d_out+(size_t)4*N);
  int* bsum=(int*)((char*)d_out+(size_t)4*N);   // scan scratch, dead before scatter

  int NBn=(N+NT-1)/NT, nbE=(E+NT-1)/NT;
  int nscan=in_sizes[0]*2; if(nscan>512) nscan=512;

  hipMemsetAsync(rowc,0,(size_t)N*sizeof(int),stream);
  k_probe  <<<1,64,0,stream>>>((const unsigned short*)x,nscan,stats);
  k_prep   <<<1024,NT,0,stream>>>(ea,idx,rowc,stats,E,N);
  k_node1  <<<NBn,NT,0,stream>>>(x,W1,as1,ad1,stats,als,ald,N);
  k_scan1  <<<NBn,NT,0,stream>>>(rowc,bsum,N);
  k_scan2  <<<1,1024,0,stream>>>(bsum,NBn);
  k_scan3  <<<NBn,NT,0,stream>>>(rowc,bsum,N);
  k_scatter<<<nbE,NT,0,stream>>>(idx,ea,We1,ae1,als,stats,rowc,csr,E,N);
  k_gather1<<<(N+15)/16,NT,0,stream>>>(csr,rowc,als,ald,x,W1,b1,W2,as2,ad2,We1,ae1,
                                       stats,invE,h1,h2,als,ald2,N);
  k_seed   <<<NBn,NT,0,stream>>>(amaxu,N);
  k_edge2  <<<nbE,NT,0,stream>>>(idx,ea,h1,als,ald2,mw0,mb0,mw1,mb1,mw2,mb2,mw3,mb3,
                                 We2,ae2,amaxu,stats,d_out,E,N);
  k_node2b <<<NBn,NT,0,stream>>>(stats,invE,als,ald2,We2,ae2,h2,amaxu,den2,acc2,N);
  k_edge2b <<<nbE,NT,0,stream>>>(idx,ea,h1,als,ald2,mw0,mb0,mw1,mb1,mw2,mb2,mw3,mb3,
                                 We2,ae2,stats,amaxf,h2,den2,acc2,E,N);
  k_node3  <<<NBn,NT,0,stream>>>(den2,acc2,bias2,stats,d_out,N);
}